// Round 3
// baseline (38185.773 us; speedup 1.0000x reference)
//
#include <hip/hip_runtime.h>
#include <hip/hip_bf16.h>
#include <hip/hip_fp16.h>

// Hypernetwork RNN scan. B=16, N=2048, M=H=64, L*E=1024, Cout=256.
// Round 16: single-WG-per-batch with EXPLICIT AGPR storage.
// R15 post-mortem: CDNA architected VGPRs cap at 256/lane; the other 256
// regs of the 1-wave/SIMD file are AGPRs, which LLVM won't use for plain
// arrays in MFMA-free kernels (spills went to scratch: VGPR_Count=256,
// 11-18 GB FETCH). Fix: place Wd across all three on-CU storage classes:
//   hl 0..5  -> arch VGPRs  (wreg[48] = 192 regs)
//   hl 6..12 -> AGPRs       (224 regs, v_accvgpr_write/read inline asm)
//   hl 13..15-> resident LDS (96 KB)
// Per-step: 512 dot2 + 224 accvgpr_read + 24 ds_read_b128 per thread,
// zero global traffic, zero inter-WG traffic. f32 chains bit-identical
// to R13/R14/R15 (absmax 0.0625 preserved).
//   K1 cvt: Wd->f16 per-thread layout; enc m-rows->f16; dec_w->bf16
//   K2 build_T (f32, 8 MB), K3 build_P (f32, 16 MB)
//   K4 recur: 16 WGs = 16 batches; Wd in VGPR+AGPR+LDS
//   K5 loss:  parallel logits/LSE/NLL over the f16 m history

typedef unsigned int uint_t;
typedef unsigned short us_t;
typedef _Float16 h2_t __attribute__((ext_vector_type(2)));

__device__ __forceinline__ us_t f2bf(float f) {
    uint_t u = __float_as_uint(f);
    uint_t r = u + 0x7fffu + ((u >> 16) & 1u);   // RNE
    return (us_t)(r >> 16);
}
__device__ __forceinline__ float bflo(uint_t u) { return __uint_as_float(u << 16); }
__device__ __forceinline__ float bfhi(uint_t u) { return __uint_as_float(u & 0xffff0000u); }

__device__ __forceinline__ us_t f2h(float f) {
    __half h = __float2half(f);                  // RNE
    return *reinterpret_cast<us_t*>(&h);
}
__device__ __forceinline__ float h2f(us_t s) {
    __half h = *reinterpret_cast<__half*>(&s);
    return __half2float(h);
}
__device__ __forceinline__ h2_t u2h2(uint_t u) {
    union { uint_t u; h2_t h; } x; x.u = u; return x.h;
}

#if __has_builtin(__builtin_amdgcn_fdot2)
__device__ __forceinline__ float dot2f(uint_t a, uint_t b, float c) {
    return __builtin_amdgcn_fdot2(u2h2(a), u2h2(b), c, false);
}
#else
__device__ __forceinline__ float dot2f(uint_t a, uint_t b, float c) {
    h2_t x = u2h2(a), y = u2h2(b);
    return c + (float)x.x * (float)y.x + (float)x.y * (float)y.y;
}
#endif

#define DOT4C(q, mc, acc)                                               \
    acc = dot2f(q.x, mc.x, acc);                                        \
    acc = dot2f(q.y, mc.y, acc);                                        \
    acc = dot2f(q.z, mc.z, acc);                                        \
    acc = dot2f(q.w, mc.w, acc);

// ---- AGPR storage machinery (hl = 6..12, jp = 0..7, word = 0..3) ----
#define AGDECL(hl)                                                      \
    uint_t ag##hl##_0_0, ag##hl##_0_1, ag##hl##_0_2, ag##hl##_0_3,      \
           ag##hl##_1_0, ag##hl##_1_1, ag##hl##_1_2, ag##hl##_1_3,      \
           ag##hl##_2_0, ag##hl##_2_1, ag##hl##_2_2, ag##hl##_2_3,      \
           ag##hl##_3_0, ag##hl##_3_1, ag##hl##_3_2, ag##hl##_3_3,      \
           ag##hl##_4_0, ag##hl##_4_1, ag##hl##_4_2, ag##hl##_4_3,      \
           ag##hl##_5_0, ag##hl##_5_1, ag##hl##_5_2, ag##hl##_5_3,      \
           ag##hl##_6_0, ag##hl##_6_1, ag##hl##_6_2, ag##hl##_6_3,      \
           ag##hl##_7_0, ag##hl##_7_1, ag##hl##_7_2, ag##hl##_7_3;

#define AGINIT(hl, jp) {                                                \
    uint4 q = g4[((hl) * 8 + (jp)) * 256 + tid];                        \
    asm volatile("v_accvgpr_write_b32 %0, %1"                           \
                 : "=a"(ag##hl##_##jp##_0) : "v"(q.x));                 \
    asm volatile("v_accvgpr_write_b32 %0, %1"                           \
                 : "=a"(ag##hl##_##jp##_1) : "v"(q.y));                 \
    asm volatile("v_accvgpr_write_b32 %0, %1"                           \
                 : "=a"(ag##hl##_##jp##_2) : "v"(q.z));                 \
    asm volatile("v_accvgpr_write_b32 %0, %1"                           \
                 : "=a"(ag##hl##_##jp##_3) : "v"(q.w)); }

#define AGINIT_ROW(hl)                                                  \
    AGINIT(hl, 0) AGINIT(hl, 1) AGINIT(hl, 2) AGINIT(hl, 3)             \
    AGINIT(hl, 4) AGINIT(hl, 5) AGINIT(hl, 6) AGINIT(hl, 7)

// volatile reads: must NOT be hoisted out of the t-loop (224 live VGPRs
// would recreate the R15 spill). Re-read from AGPR every step.
#define DOTA(hl, jp) {                                                  \
    uint_t w0, w1, w2, w3;                                              \
    asm volatile("v_accvgpr_read_b32 %0, %1"                            \
                 : "=v"(w0) : "a"(ag##hl##_##jp##_0));                  \
    asm volatile("v_accvgpr_read_b32 %0, %1"                            \
                 : "=v"(w1) : "a"(ag##hl##_##jp##_1));                  \
    asm volatile("v_accvgpr_read_b32 %0, %1"                            \
                 : "=v"(w2) : "a"(ag##hl##_##jp##_2));                  \
    asm volatile("v_accvgpr_read_b32 %0, %1"                            \
                 : "=v"(w3) : "a"(ag##hl##_##jp##_3));                  \
    va[hl] = dot2f(w0, mc.x, va[hl]);                                   \
    va[hl] = dot2f(w1, mc.y, va[hl]);                                   \
    va[hl] = dot2f(w2, mc.z, va[hl]);                                   \
    va[hl] = dot2f(w3, mc.w, va[hl]); }

#define DOTR(hl, jp) {                                                  \
    uint4 q = wreg[(hl) * 8 + (jp)];                                    \
    DOT4C(q, mc, va[hl]); }

#define VSTEP(jp) {                                                     \
    uint4 mc = m4[jp];                                                  \
    uint4 q13 = wlds4[(0 * 8 + (jp)) * 256 + tid];                      \
    uint4 q14 = wlds4[(1 * 8 + (jp)) * 256 + tid];                      \
    uint4 q15 = wlds4[(2 * 8 + (jp)) * 256 + tid];                      \
    DOTR(0, jp) DOTR(1, jp) DOTR(2, jp)                                 \
    DOTR(3, jp) DOTR(4, jp) DOTR(5, jp)                                 \
    DOTA(6, jp) DOTA(7, jp) DOTA(8, jp) DOTA(9, jp)                     \
    DOTA(10, jp) DOTA(11, jp) DOTA(12, jp)                              \
    DOT4C(q13, mc, va[13]);                                             \
    DOT4C(q14, mc, va[14]);                                             \
    DOT4C(q15, mc, va[15]); }

// ---------------- K1: convert/swizzle weights ----------------
// WdG  [c<128][tid<256][e<8] f16 (uint4 at c*256+tid lane-contiguous):
//      tid -> hg=tid>>6, i=tid&63;  c -> hl=c>>3, jp=c&7
//      h = hg*16 + hl,  j = jp*8 + e
//      val = Wd[h][i*64 + j]   (per-thread register/LDS layout for recur)
// decwY [mm<64][lane<64][k<4] bf16: val = decw[mm*256 + k*64 + lane]
// EWmG [jp<8][h2<128][k<8] f16: val = enc_m_row(j=jp*8+k, h2)
__global__ void cvt_kernel(const float* __restrict__ Wdecw,
                           const float* __restrict__ decw,
                           const float* __restrict__ Wencw,
                           const float* __restrict__ bencw,
                           us_t* __restrict__ WdG, us_t* __restrict__ decwY,
                           us_t* __restrict__ EWmG) {
    int o = blockIdx.x * 256 + threadIdx.x;
    if (o < 262144) {
        int e = o & 7;
        int tq = (o >> 3) & 255;
        int c = o >> 11;
        int hg = tq >> 6, i = tq & 63;
        int hl = c >> 3, jp = c & 7;
        int h = hg * 16 + hl;
        int j = jp * 8 + e;
        WdG[o] = f2h(Wdecw[h * 4096 + i * 64 + j]);
    } else if (o < 278528) {
        int oo = o - 262144;
        int k = oo & 3, lane = (oo >> 2) & 63, mm = oo >> 8;
        decwY[oo] = f2bf(decw[mm * 256 + k * 64 + lane]);
    } else if (o < 286720) {
        int oo = o - 278528;
        int kk = oo & 7, h2 = (oo >> 3) & 127, jp = oo >> 10;
        int j = jp * 8 + kk;
        float v = (h2 < 64) ? Wencw[j * 64 + h2] : bencw[j * 64 + (h2 - 64)];
        EWmG[oo] = f2h(v);
    }
}

// ---------------- K2: token contribution table ----------------
__global__ void build_T(const float* __restrict__ emb, const float* __restrict__ Wencw,
                        const float* __restrict__ bencw, float* __restrict__ T) {
    int l = blockIdx.x >> 8, v = blockIdx.x & 255, h2 = threadIdx.x;  // h2 < 128
    float acc = 0.f;
#pragma unroll
    for (int e = 0; e < 16; ++e) {
        int d = 64 + l * 16 + e;
        float w = (h2 < 64) ? Wencw[d * 64 + h2] : bencw[d * 64 + (h2 - 64)];
        acc += emb[v * 16 + e] * w;
    }
    T[blockIdx.x * 128 + h2] = acc;
}

// ---------------- K3: window precompute P (f32) ----------------
__global__ void build_P(const float* __restrict__ T, const int* __restrict__ x0,
                        const float* __restrict__ Wencb, const float* __restrict__ bencb,
                        float* __restrict__ P) {
    int t = blockIdx.x >> 4, b = blockIdx.x & 15, h2 = threadIdx.x;  // h2 < 128
    float acc = (h2 < 64) ? Wencb[h2] : bencb[h2 - 64];
    for (int l = 0; l < 64; ++l) {
        int p = t + l;
        int v = (p < 64) ? 0 : x0[b * 2048 + (p - 64)];
        acc += T[(l * 256 + v) * 128 + h2];
    }
    P[blockIdx.x * 128 + h2] = acc;
}

// ---------------- K4: sequential recurrence (single WG per batch) ----------
// grid 16: b = blockIdx.x. 256 threads = 4 waves = 1 wave/SIMD.
// Wd: 192 arch VGPRs + 224 AGPRs + 96 KB LDS per thread-slice partition.
__global__ __launch_bounds__(256, 1) void recur(
    const float* __restrict__ bdecw, const float* __restrict__ bdecb,
    const float* __restrict__ Wdecb, const us_t* __restrict__ WdG,
    const us_t* __restrict__ EWmG, const float* __restrict__ P,
    uint_t* __restrict__ mh32) {
    const int b = blockIdx.x;
    const int tid = threadIdx.x;

    extern __shared__ char smem[];
    uint4*  wlds4   = (uint4*)(smem);              // 98304 [c<24][tid<256] uint4
    us_t*   EWm2    = (us_t*)(smem + 98304);       // 16384 [jp][h2][8] f16
    uint_t* wdbt2   = (uint_t*)(smem + 114688);    // 8192 [jj<32][i<64] Wdb f16 pairs
    uint_t* bdec2   = (uint_t*)(smem + 122880);    // 8192 [hh<32][i<64] bdec f16 pairs
    float*  rp_s    = (float*)(smem + 131072);     // 1024 [hg<4][i<64]
    float*  wdbm2_s = (float*)(smem + 132096);     // 512  [q<2][i]
    float*  hbb2_s  = (float*)(smem + 132608);     // 512  [q<2][i]
    float*  hw_s    = (float*)(smem + 133120);     // 256
    uint_t* hb2_s   = (uint_t*)(smem + 133376);    // 128 packed f16 hb pairs
    uint_t* m2_s    = (uint_t*)(smem + 133504);    // 128 packed f16 m pairs
    float*  bias_s  = (float*)(smem + 133632);     // 256
    // total 133888 (dynamic; attribute set at launch). 1 WG/CU.

    // AGPR-resident Wd rows hl = 6..12 (224 AGPRs)
    AGDECL(6) AGDECL(7) AGDECL(8) AGDECL(9) AGDECL(10) AGDECL(11) AGDECL(12)

    // ---- init: Wd hl 0..5 -> arch regs, 6..12 -> AGPRs, 13..15 -> LDS ----
    uint4 wreg[48];
    {
        const uint4* g4 = (const uint4*)WdG;
#pragma unroll
        for (int c = 0; c < 48; ++c) wreg[c] = g4[c * 256 + tid];
        AGINIT_ROW(6) AGINIT_ROW(7) AGINIT_ROW(8) AGINIT_ROW(9)
        AGINIT_ROW(10) AGINIT_ROW(11) AGINIT_ROW(12)
        for (int c = 104; c < 128; ++c) wlds4[(c - 104) * 256 + tid] = g4[c * 256 + tid];
    }
    {
        const uint4* g4 = (const uint4*)EWmG;
        uint4* l4 = (uint4*)EWm2;
        for (int k = tid; k < 1024; k += 256) l4[k] = g4[k];
    }
    for (int k = tid; k < 2048; k += 256) {
        int jj = k >> 6, i = k & 63;
        wdbt2[k] = (uint_t)f2h(Wdecb[i * 64 + 2 * jj])
                 | ((uint_t)f2h(Wdecb[i * 64 + 2 * jj + 1]) << 16);
        bdec2[k] = (uint_t)f2h(bdecw[(2 * jj) * 64 + i])
                 | ((uint_t)f2h(bdecw[(2 * jj + 1) * 64 + i]) << 16);
    }
    if (tid < 64) bias_s[tid] = bdecb[tid];
    if (tid < 32) m2_s[tid] = 0u;
    __syncthreads();

    float preg = 0.f;
    if (tid < 128) preg = P[b * 128 + tid];  // t = 0

    const uint4* EW4 = (const uint4*)EWm2;
    const uint4* m4 = (const uint4*)m2_s;
    const int hg = tid >> 6, iA = tid & 63;

    for (int t = 0; t < 2048; ++t) {
        // ---- phase A: P prefetch; henc (waves 0-1); V (all); Wdb*m (2-3) ----
        float pnext = 0.f;
        int tp = (t < 2047) ? (t + 1) : 2047;
        if (tid < 128) pnext = P[(tp * 16 + b) * 128 + tid];

        if (tid < 128) {
            float acc = preg;
#pragma unroll
            for (int jp = 0; jp < 8; ++jp) {
                uint4 e = EW4[jp * 128 + tid];
                uint4 mc = m4[jp];
                DOT4C(e, mc, acc);
            }
            float sg = 1.f / (1.f + __expf(-acc));
            if (tid < 64) {
                hw_s[tid] = sg;
            } else {
                int l = tid - 64;            // lane within wave 1
                float vlo = __shfl(sg, (l & 31) * 2, 64);
                float vhi = __shfl(sg, (l & 31) * 2 + 1, 64);
                if (l < 32)
                    hb2_s[l] = (uint_t)f2h(vlo) | ((uint_t)f2h(vhi) << 16);
            }
        }

        // V[h][iA] for this thread's 16 h-rows. hl 0..5 arch regs,
        // 6..12 AGPRs (volatile accvgpr_read per step), 13..15 LDS.
        // Chain per (h,i): jp ascending, word ascending - identical to R15.
        float va[16];
#pragma unroll
        for (int hl = 0; hl < 16; ++hl) va[hl] = 0.f;
        VSTEP(0) VSTEP(1) VSTEP(2) VSTEP(3)
        VSTEP(4) VSTEP(5) VSTEP(6) VSTEP(7)

        if (hg >= 2) {                       // Wdb*m local term (needs only m)
            int q = hg - 2;
            float wm = 0.f;
#pragma unroll
            for (int jj = 0; jj < 16; ++jj)
                wm = dot2f(wdbt2[(q * 16 + jj) * 64 + iA], m2_s[q * 16 + jj], wm);
            wdbm2_s[q * 64 + iA] = wm;
        }
        preg = pnext;
        __syncthreads();   // sync1

        // ---- phase B: hw-weighted slice sum from OWN V regs; bdec*hb ----
        {
            float r0 = 0.f, r1 = 0.f;
#pragma unroll
            for (int hh = 0; hh < 8; ++hh) {
                r0 += hw_s[hg * 16 + 2 * hh]     * va[2 * hh];
                r1 += hw_s[hg * 16 + 2 * hh + 1] * va[2 * hh + 1];
            }
            rp_s[hg * 64 + iA] = r0 + r1;    // slice hg's rs (= R13 r0+r1)
        }
        if (hg >= 2) {                       // bdec*hb (needs hb from sync1)
            int q = hg - 2;
            float hbv = 0.f;
#pragma unroll
            for (int jj = 0; jj < 16; ++jj)
                hbv = dot2f(bdec2[(q * 16 + jj) * 64 + iA], hb2_s[q * 16 + jj], hbv);
            hbb2_s[q * 64 + iA] = hbv;
        }
        __syncthreads();   // sync2

        // ---- phase C: assemble m (order bit-identical to R13/R14/R15) ----
        if (tid < 64) {
            float rs01 = rp_s[tid] + rp_s[64 + tid];          // rs0 + rs1
            float rs23 = rp_s[128 + tid] + rp_s[192 + tid];   // rs2 + rs3
            float r = (rs01 + rs23)
                    + (wdbm2_s[tid] + wdbm2_s[64 + tid])
                    + (hbb2_s[tid] + hbb2_s[64 + tid])
                    + bias_s[tid];
            float nm = 1.f / (1.f + __expf(-r));
            us_t nh = f2h(nm);                  // f16 round (history dtype)
            uint_t nhu = (uint_t)nh;
            uint_t lo = (uint_t)__shfl((int)nhu, (tid & 31) * 2, 64);
            uint_t hi = (uint_t)__shfl((int)nhu, (tid & 31) * 2 + 1, 64);
            if (tid < 32) {
                uint_t pk = lo | (hi << 16);
                m2_s[tid] = pk;
                mh32[(t * 16 + b) * 32 + tid] = pk;  // history
            }
        }
        __syncthreads();   // sync3
    }
}

// ---------------- K5: parallel loss (reads f16 m history) ----------------
__global__ __launch_bounds__(256) void loss_kernel(
    const us_t* __restrict__ mhb, const us_t* __restrict__ decwY,
    const float* __restrict__ decb, const int* __restrict__ x0,
    float* __restrict__ out) {
    __shared__ __align__(16) us_t dw[16384];   // [mm][lane][k<4] bf16
    const int tid = threadIdx.x;
    {
        const uint4* g4 = (const uint4*)decwY;
        uint4* l4 = (uint4*)dw;
        for (int k = tid; k < 2048; k += 256) l4[k] = g4[k];
    }
    __syncthreads();
    const int lane = tid & 63, wv = tid >> 6;
    const uint2* dwu2 = (const uint2*)dw;
    float b0 = decb[lane], b1 = decb[lane + 64];
    float b2 = decb[lane + 128], b3 = decb[lane + 192];
    for (int r = 0; r < 8; ++r) {
        int row = blockIdx.x * 32 + wv * 8 + r;
        float mL = h2f(mhb[row * 64 + lane]);
        float l0 = b0, l1 = b1, l2 = b2, l3 = b3;
#pragma unroll
        for (int mm = 0; mm < 64; ++mm) {
            float mv = __shfl(mL, mm, 64);
            uint2 q = dwu2[mm * 64 + lane];
            l0 += mv * bflo(q.x);
            l1 += mv * bfhi(q.x);
            l2 += mv * bflo(q.y);
            l3 += mv * bfhi(q.y);
        }
        float mx = fmaxf(fmaxf(l0, l1), fmaxf(l2, l3));
#pragma unroll
        for (int o = 32; o > 0; o >>= 1) mx = fmaxf(mx, __shfl_xor(mx, o, 64));
        float se = __expf(l0 - mx) + __expf(l1 - mx) + __expf(l2 - mx) + __expf(l3 - mx);
#pragma unroll
        for (int o = 32; o > 0; o >>= 1) se += __shfl_xor(se, o, 64);
        float lse = mx + __logf(se);
        int t = row >> 4, bb = row & 15;
        int y = x0[bb * 2048 + t];
        int hi = y >> 6;
        float cand = hi == 0 ? l0 : (hi == 1 ? l1 : (hi == 2 ? l2 : l3));
        float ly = __shfl(cand, y & 63, 64);
        if (lane == 0) out[row] = (lse - ly) * 1.4426950408889634f;
    }
}

extern "C" void kernel_launch(void* const* d_in, const int* in_sizes, int n_in,
                              void* d_out, int out_size, void* d_ws, size_t ws_size,
                              hipStream_t stream) {
    const int*   x0    = (const int*)d_in[0];
    const float* emb   = (const float*)d_in[1];
    const float* Wencw = (const float*)d_in[2];
    const float* Wencb = (const float*)d_in[3];
    const float* Wdecw = (const float*)d_in[4];
    const float* Wdecb = (const float*)d_in[5];
    const float* bencw = (const float*)d_in[6];
    const float* bencb = (const float*)d_in[7];
    const float* bdecw = (const float*)d_in[8];
    const float* bdecb = (const float*)d_in[9];
    const float* decw  = (const float*)d_in[10];
    const float* decb  = (const float*)d_in[11];
    float* out = (float*)d_out;

    char* ws = (char*)d_ws;
    us_t*   WdG   = (us_t*)(ws);                 //       0 .. 524288
    us_t*   decwY = (us_t*)(ws + 524288);        //  524288 .. 557056
    us_t*   EWmG  = (us_t*)(ws + 557056);        //  557056 .. 573440 (16 KB)
    float*  T     = (float*)(ws + 638976);       //  638976 .. 9027584 (8 MB)
    uint_t* mh32  = (uint_t*)T;                  //  alias: T dead after build_P (4 MB)
    float*  P     = (float*)(ws + 9027584);      // 9027584 .. 25804800 (16 MB)

    static const int kRecurLds = 133888;
    (void)hipFuncSetAttribute((const void*)recur,
                              hipFuncAttributeMaxDynamicSharedMemorySize,
                              kRecurLds);

    cvt_kernel<<<1120, 256, 0, stream>>>(Wdecw, decw, Wencw, bencw,
                                         WdG, decwY, EWmG);
    build_T<<<16384, 128, 0, stream>>>(emb, Wencw, bencw, T);
    build_P<<<32768, 128, 0, stream>>>(T, x0, Wencb, bencb, P);
    recur<<<16, 256, kRecurLds, stream>>>(bdecw, bdecb, Wdecb, WdG, EWmG,
                                          P, mh32);
    loss_kernel<<<1024, 256, 0, stream>>>((const us_t*)mh32, decwY, decb, x0, out);
}

// Round 5
// 3706.183 us; speedup vs baseline: 10.3033x; 10.3033x over previous
//
#include <hip/hip_runtime.h>
#include <hip/hip_bf16.h>
#include <hip/hip_fp16.h>

// Hypernetwork RNN scan. B=16, N=2048, M=H=64, L*E=1024, Cout=256.
// Round 18: R13 structure + XCD-local fast exchange, HARDENED.
// R17 failed opaquely; this round removes every identified hang/compile
// hazard while keeping the same idea:
//  - role assignment: global 64-entry CAS table; WG prefers the 8 roles
//    of its own XCD (XCC_ID via __builtin_amdgcn_s_getreg id=20) then
//    scans all 64 -> total coverage under ANY XCC_ID behavior; exactly
//    64 winners on 64 distinct CUs (1 WG/CU by 157KB LDS), all others
//    exit. Deadlock impossible: winners are resident by construction.
//  - exchange: producers double-publish r_s: plain store to an
//    XCD-LOCAL slot (local L2; consumer reads it with sc0 = GLC:
//    L1-bypass, L2-served) AND R13's agent-scope store (LLC backstop).
//    Consumers spin <=64 iters on the local slot, then STICKY-fallback
//    to R13's agent poll. Wrong placement/coherence -> R13 speed, not
//    a hang.
// All arithmetic/phases/orders byte-identical to R13 (absmax 0.0625).
//   K1 cvt: Wd->f16 h-slice layout; enc m-rows->f16; dec_w->bf16 (loss)
//   K2 build_T (f32, 8 MB), K3 build_P (f32, 16 MB)
//   K4 recur: 256 WGs -> 64 workers = 16 batches x 4 h-slices
//   K5 loss:  parallel logits/LSE/NLL over the f16 m history

typedef unsigned int uint_t;
typedef unsigned short us_t;
typedef unsigned long long u64_t;
typedef _Float16 h2_t __attribute__((ext_vector_type(2)));

__device__ __forceinline__ us_t f2bf(float f) {
    uint_t u = __float_as_uint(f);
    uint_t r = u + 0x7fffu + ((u >> 16) & 1u);   // RNE
    return (us_t)(r >> 16);
}
__device__ __forceinline__ float bflo(uint_t u) { return __uint_as_float(u << 16); }
__device__ __forceinline__ float bfhi(uint_t u) { return __uint_as_float(u & 0xffff0000u); }

__device__ __forceinline__ us_t f2h(float f) {
    __half h = __float2half(f);                  // RNE
    return *reinterpret_cast<us_t*>(&h);
}
__device__ __forceinline__ float h2f(us_t s) {
    __half h = *reinterpret_cast<__half*>(&s);
    return __half2float(h);
}
__device__ __forceinline__ h2_t u2h2(uint_t u) {
    union { uint_t u; h2_t h; } x; x.u = u; return x.h;
}

#if __has_builtin(__builtin_amdgcn_fdot2)
__device__ __forceinline__ float dot2f(uint_t a, uint_t b, float c) {
    return __builtin_amdgcn_fdot2(u2h2(a), u2h2(b), c, false);
}
#else
__device__ __forceinline__ float dot2f(uint_t a, uint_t b, float c) {
    h2_t x = u2h2(a), y = u2h2(b);
    return c + (float)x.x * (float)y.x + (float)x.y * (float)y.y;
}
#endif

#define DOT4(q, base, acc)                                              \
    acc = dot2f(q.x, mreg2u[(base) + 0], acc);                          \
    acc = dot2f(q.y, mreg2u[(base) + 1], acc);                          \
    acc = dot2f(q.z, mreg2u[(base) + 2], acc);                          \
    acc = dot2f(q.w, mreg2u[(base) + 3], acc);

// XCD-local mailbox ops. Store: plain (write-through to this XCD's L2).
// Load: sc0 (= legacy GLC: bypass L1, served by L2). Valid fast only when
// producer+consumer share an XCD; otherwise the sticky fallback covers it.
__device__ __forceinline__ void l2_store_u64(u64_t* p, u64_t v) {
    asm volatile("global_store_dwordx2 %0, %1, off"
                 :: "v"(p), "v"(v) : "memory");
}
__device__ __forceinline__ u64_t l2_load_u64(const u64_t* p) {
    u64_t v;
    asm volatile("global_load_dwordx2 %0, %1, off sc0\n\t"
                 "s_waitcnt vmcnt(0)"
                 : "=v"(v) : "v"(p) : "memory");
    return v;
}

// ---------------- K1: convert/swizzle weights ----------------
// WdG  [s<4][jp<8][o<1024][k<8] f16: h = s*16 + (o>>6), i = o&63, j = jp*8+k
//      val = Wd[h][i*64 + j]   (h-slice layout; uint4 at jp*1024+o lane-contig)
// decwY [mm<64][lane<64][k<4] bf16: val = decw[mm*256 + k*64 + lane]
// EWmG [jp<8][h2<128][k<8] f16: val = enc_m_row(j=jp*8+k, h2)
__global__ void cvt_kernel(const float* __restrict__ Wdecw,
                           const float* __restrict__ decw,
                           const float* __restrict__ Wencw,
                           const float* __restrict__ bencw,
                           us_t* __restrict__ WdG, us_t* __restrict__ decwY,
                           us_t* __restrict__ EWmG) {
    int o = blockIdx.x * 256 + threadIdx.x;
    if (o < 262144) {
        int s = o >> 16;
        int idx = o & 65535;
        int k = idx & 7;
        int oo = (idx >> 3) & 1023;
        int jp = idx >> 13;
        int h = s * 16 + (oo >> 6);
        int i = oo & 63;
        int j = jp * 8 + k;
        WdG[o] = f2h(Wdecw[h * 4096 + i * 64 + j]);
    } else if (o < 278528) {
        int oo = o - 262144;
        int k = oo & 3, lane = (oo >> 2) & 63, mm = oo >> 8;
        decwY[oo] = f2bf(decw[mm * 256 + k * 64 + lane]);
    } else if (o < 286720) {
        int oo = o - 278528;
        int kk = oo & 7, h2 = (oo >> 3) & 127, jp = oo >> 10;
        int j = jp * 8 + kk;
        float v = (h2 < 64) ? Wencw[j * 64 + h2] : bencw[j * 64 + (h2 - 64)];
        EWmG[oo] = f2h(v);
    }
}

// ---------------- K2: token contribution table ----------------
__global__ void build_T(const float* __restrict__ emb, const float* __restrict__ Wencw,
                        const float* __restrict__ bencw, float* __restrict__ T) {
    int l = blockIdx.x >> 8, v = blockIdx.x & 255, h2 = threadIdx.x;  // h2 < 128
    float acc = 0.f;
#pragma unroll
    for (int e = 0; e < 16; ++e) {
        int d = 64 + l * 16 + e;
        float w = (h2 < 64) ? Wencw[d * 64 + h2] : bencw[d * 64 + (h2 - 64)];
        acc += emb[v * 16 + e] * w;
    }
    T[blockIdx.x * 128 + h2] = acc;
}

// ---------------- K3: window precompute P (f32) ----------------
__global__ void build_P(const float* __restrict__ T, const int* __restrict__ x0,
                        const float* __restrict__ Wencb, const float* __restrict__ bencb,
                        float* __restrict__ P) {
    int t = blockIdx.x >> 4, b = blockIdx.x & 15, h2 = threadIdx.x;  // h2 < 128
    float acc = (h2 < 64) ? Wencb[h2] : bencb[h2 - 64];
    for (int l = 0; l < 64; ++l) {
        int p = t + l;
        int v = (p < 64) ? 0 : x0[b * 2048 + (p - 64)];
        acc += T[(l * 256 + v) * 128 + h2];
    }
    P[blockIdx.x * 128 + h2] = acc;
}

// ---------------- K4: sequential recurrence (h-slice, hardened) ----------
// grid 256 (1 WG/CU via LDS). Role claim: prefer own-XCD roles, then any.
__global__ __launch_bounds__(512, 2) void recur(
    const float* __restrict__ bdecw, const float* __restrict__ bdecb,
    const float* __restrict__ Wdecb, const us_t* __restrict__ WdG,
    const us_t* __restrict__ EWmG, const float* __restrict__ P,
    uint_t* __restrict__ mh32, u64_t* __restrict__ pxbA,
    u64_t* __restrict__ pxbL, uint_t* __restrict__ claimed) {
    const int tid = threadIdx.x;

    extern __shared__ char smem[];
    us_t*   EWm2   = (us_t*)(smem);                // 16384 [jp][h2][8] f16
    uint_t* wdbt2  = (uint_t*)(smem + 16384);      // 8192 [jj<32][i<64]: (Wdb[i][2jj],Wdb[i][2jj+1]) f16
    uint_t* bdec2  = (uint_t*)(smem + 24576);      // 8192 [hh<32][i<64]: (bdec[2hh][i],bdec[2hh+1][i]) f16
    float*  V_s    = (float*)(smem + 32768);       // 4160 [hl<16][i<64] stride 65
    float*  rp4_s  = (float*)(smem + 36928);       // 1024 [p<4][i]
    float*  wdbm2_s= (float*)(smem + 37952);       // 512  [q<2][i]
    float*  hbb2_s = (float*)(smem + 38464);       // 512  [q<2][i]
    float*  hw_s   = (float*)(smem + 38976);       // 256
    uint_t* hb2_s  = (uint_t*)(smem + 39232);      // 128 packed f16 hb pairs
    uint_t* m2_s   = (uint_t*)(smem + 39360);      // 128 packed f16 m pairs
    float*  bias_s = (float*)(smem + 39488);       // 256
    int*    role_p = (int*)(smem + 39744);         // 4 (in the pad region)
    // live total 39748; pad to 157632 at launch (1 WG/CU)

    // ---- claim a role: prefer this XCD's 8 roles, else scan all 64 ----
    if (tid == 0) {
        // HW_REG_XCC_ID = hwreg id 20 (CDNA3/4); size 32, offset 0.
        uint_t xcc = __builtin_amdgcn_s_getreg((31u << 11) | 20u) & 7u;
        int role = -1;
#pragma unroll 1
        for (int k = 0; k < 8; ++k) {
            int r = (int)xcc * 8 + k;
            if (atomicCAS(&claimed[r], 0u, 1u) == 0u) { role = r; break; }
        }
        if (role < 0) {
#pragma unroll 1
            for (int r = 0; r < 64; ++r)
                if (atomicCAS(&claimed[r], 0u, 1u) == 0u) { role = r; break; }
        }
        *role_p = role;
    }
    __syncthreads();
    const int role = *role_p;
    if (role < 0) return;                  // spare WG: this CU idles
    const int b = role >> 2;
    const int s = role & 3;

    // ---- init: Wd h-slice -> registers (rows o=tid, o=tid+512) ----
    uint4 wreg[16];
    {
        const uint4* g4 = (const uint4*)WdG + s * 8192;
#pragma unroll
        for (int jp = 0; jp < 8; ++jp) {
            wreg[jp]     = g4[jp * 1024 + tid];
            wreg[8 + jp] = g4[jp * 1024 + tid + 512];
        }
    }
    {
        const uint4* g4 = (const uint4*)EWmG;
        uint4* l4 = (uint4*)EWm2;
        for (int k = tid; k < 1024; k += 512) l4[k] = g4[k];
    }
    for (int k = tid; k < 2048; k += 512) {
        int jj = k >> 6, i = k & 63;
        wdbt2[k] = (uint_t)f2h(Wdecb[i * 64 + 2 * jj])
                 | ((uint_t)f2h(Wdecb[i * 64 + 2 * jj + 1]) << 16);
        bdec2[k] = (uint_t)f2h(bdecw[(2 * jj) * 64 + i])
                 | ((uint_t)f2h(bdecw[(2 * jj + 1) * 64 + i]) << 16);
    }
    if (tid < 64) bias_s[tid] = bdecb[tid];
    if (tid < 32) m2_s[tid] = 0u;
    __syncthreads();

    // persistent m as 32 packed half2 regs; COMPILE-TIME indexing only
    // (Round-3 lesson: any runtime index demotes the array to scratch).
    uint_t mreg2u[32];
#pragma unroll
    for (int j = 0; j < 32; ++j) mreg2u[j] = 0u;

    float preg = 0.f;
    if (tid < 128) preg = P[b * 128 + tid];  // t = 0

    const uint4* EW4 = (const uint4*)EWm2;
    const int hl = tid >> 6, iA = tid & 63;
    const int w = tid >> 6;   // wave index
    int fastok = 1;           // sticky: wave-uniform (ballot-driven) switch

    for (int t = 0; t < 2048; ++t) {
        // ---- phase A: P prefetch; V slice (Wd regs); henc; hb pack ----
        float pnext = 0.f;
        int tp = (t < 2047) ? (t + 1) : 2047;
        if (tid < 128) pnext = P[(tp * 16 + b) * 128 + tid];

        float a0 = 0.f, a1 = 0.f;
#pragma unroll
        for (int jp = 0; jp < 8; ++jp) {
            uint4 q0 = wreg[jp];
            uint4 q1 = wreg[8 + jp];
            DOT4(q0, jp * 4, a0);
            DOT4(q1, jp * 4, a1);
        }
        V_s[hl * 65 + iA] = a0;        // h_local = hl
        V_s[(hl + 8) * 65 + iA] = a1;  // h_local = hl + 8

        if (tid < 128) {
            float acc = preg;
#pragma unroll
            for (int jp = 0; jp < 8; ++jp) {
                uint4 e = EW4[jp * 128 + tid];
                DOT4(e, jp * 4, acc);
            }
            float sg = 1.f / (1.f + __expf(-acc));
            if (tid < 64) {
                hw_s[tid] = sg;
            } else {
                int l = tid - 64;            // lane within wave 1
                float vlo = __shfl(sg, (l & 31) * 2, 64);
                float vhi = __shfl(sg, (l & 31) * 2 + 1, 64);
                if (l < 32)
                    hb2_s[l] = (uint_t)f2h(vlo) | ((uint_t)f2h(vhi) << 16);
            }
        }
        preg = pnext;
        __syncthreads();   // sync1

        // ---- exchange phase: local-L2 fast slot + agent backstop ----
        const int slotoff = ((t & 1) * 16 + b) * 4 * 64;
        u64_t* slotLb = pxbL + slotoff;
        u64_t* slotAb = pxbA + slotoff;
        const uint_t tg = (uint_t)(t + 1);

        if (tid < 64) {
            // wave 0: own partial r_s[i] over the 16 owned h, then publish
            float r0 = 0.f, r1 = 0.f;
#pragma unroll
            for (int hh = 0; hh < 8; ++hh) {
                r0 += hw_s[s * 16 + 2 * hh]     * V_s[(2 * hh) * 65 + tid];
                r1 += hw_s[s * 16 + 2 * hh + 1] * V_s[(2 * hh + 1) * 65 + tid];
            }
            float rs = r0 + r1;
            rp4_s[s * 64 + tid] = rs;
            u64_t pay = ((u64_t)tg << 32) | (u64_t)__float_as_uint(rs);
            l2_store_u64(slotLb + s * 64 + tid, pay);           // fast
            __hip_atomic_store(slotAb + s * 64 + tid, pay,      // backstop
                               __ATOMIC_RELAXED, __HIP_MEMORY_SCOPE_AGENT);
        }

        if (w < 3) {
            // polling waves 0,1,2: one peer slot each; detection IS payload
            int p = w + (w >= s ? 1 : 0);
            int lane = tid & 63;
            const u64_t* srcL = slotLb + p * 64 + lane;
            const u64_t* srcA = slotAb + p * 64 + lane;
            u64_t v; int got = 0;
            if (fastok) {
                for (int it = 0; it < 64; ++it) {
                    v = l2_load_u64(srcL);
                    if (__ballot((uint_t)(v >> 32) == tg) == ~0ull) {
                        got = 1; break;
                    }
                    __builtin_amdgcn_s_sleep(1);
                }
                if (!got) fastok = 0;   // sticky: local slot not coherent
            }
            if (!got) {
                for (;;) {
                    v = __hip_atomic_load(srcA, __ATOMIC_RELAXED,
                                          __HIP_MEMORY_SCOPE_AGENT);
                    if (__ballot((uint_t)(v >> 32) == tg) == ~0ull) break;
                    __builtin_amdgcn_s_sleep(1);
                }
            }
            rp4_s[p * 64 + lane] = __uint_as_float((uint_t)v);
        } else if (w < 5) {
            // worker waves 3,4: local terms, overlapped with the RTT
            int i = tid & 63;
            float wm = 0.f, hbv = 0.f;
            if (w == 3) {
#pragma unroll
                for (int jj = 0; jj < 16; ++jj) {
                    wm  = dot2f(wdbt2[jj * 64 + i], mreg2u[jj], wm);
                    hbv = dot2f(bdec2[jj * 64 + i], hb2_s[jj], hbv);
                }
                wdbm2_s[i] = wm;
                hbb2_s[i] = hbv;
            } else {
#pragma unroll
                for (int jj = 0; jj < 16; ++jj) {
                    wm  = dot2f(wdbt2[(16 + jj) * 64 + i], mreg2u[16 + jj], wm);
                    hbv = dot2f(bdec2[(16 + jj) * 64 + i], hb2_s[16 + jj], hbv);
                }
                wdbm2_s[64 + i] = wm;
                hbb2_s[64 + i] = hbv;
            }
        }
        __syncthreads();   // sync2

        // ---- final: assemble identical full m locally (fixed order) ----
        if (tid < 64) {
            float r = ((rp4_s[tid] + rp4_s[64 + tid])
                     + (rp4_s[128 + tid] + rp4_s[192 + tid]))
                    + (wdbm2_s[tid] + wdbm2_s[64 + tid])
                    + (hbb2_s[tid] + hbb2_s[64 + tid])
                    + bias_s[tid];
            float nm = 1.f / (1.f + __expf(-r));
            us_t nh = f2h(nm);                  // f16 round: all WGs agree
            uint_t nhu = (uint_t)nh;
            uint_t lo = (uint_t)__shfl((int)nhu, (tid & 31) * 2, 64);
            uint_t hi = (uint_t)__shfl((int)nhu, (tid & 31) * 2 + 1, 64);
            if (tid < 32) {
                uint_t pk = lo | (hi << 16);
                m2_s[tid] = pk;
                if (s == 0) mh32[(t * 16 + b) * 32 + tid] = pk;  // history
            }
        }
        __syncthreads();   // sync3

        // ---- reload packed m into persistent registers ----
        {
            const uint4* mg = (const uint4*)m2_s;
#pragma unroll
            for (int p = 0; p < 8; ++p) {
                uint4 v = mg[p];
                mreg2u[p * 4 + 0] = v.x;
                mreg2u[p * 4 + 1] = v.y;
                mreg2u[p * 4 + 2] = v.z;
                mreg2u[p * 4 + 3] = v.w;
            }
        }
    }
}

// ---------------- K5: parallel loss (reads f16 m history) ----------------
__global__ __launch_bounds__(256) void loss_kernel(
    const us_t* __restrict__ mhb, const us_t* __restrict__ decwY,
    const float* __restrict__ decb, const int* __restrict__ x0,
    float* __restrict__ out) {
    __shared__ __align__(16) us_t dw[16384];   // [mm][lane][k<4] bf16
    const int tid = threadIdx.x;
    {
        const uint4* g4 = (const uint4*)decwY;
        uint4* l4 = (uint4*)dw;
        for (int k = tid; k < 2048; k += 256) l4[k] = g4[k];
    }
    __syncthreads();
    const int lane = tid & 63, wv = tid >> 6;
    const uint2* dwu2 = (const uint2*)dw;
    float b0 = decb[lane], b1 = decb[lane + 64];
    float b2 = decb[lane + 128], b3 = decb[lane + 192];
    for (int r = 0; r < 8; ++r) {
        int row = blockIdx.x * 32 + wv * 8 + r;
        float mL = h2f(mhb[row * 64 + lane]);
        float l0 = b0, l1 = b1, l2 = b2, l3 = b3;
#pragma unroll
        for (int mm = 0; mm < 64; ++mm) {
            float mv = __shfl(mL, mm, 64);
            uint2 q = dwu2[mm * 64 + lane];
            l0 += mv * bflo(q.x);
            l1 += mv * bfhi(q.x);
            l2 += mv * bflo(q.y);
            l3 += mv * bfhi(q.y);
        }
        float mx = fmaxf(fmaxf(l0, l1), fmaxf(l2, l3));
#pragma unroll
        for (int o = 32; o > 0; o >>= 1) mx = fmaxf(mx, __shfl_xor(mx, o, 64));
        float se = __expf(l0 - mx) + __expf(l1 - mx) + __expf(l2 - mx) + __expf(l3 - mx);
#pragma unroll
        for (int o = 32; o > 0; o >>= 1) se += __shfl_xor(se, o, 64);
        float lse = mx + __logf(se);
        int t = row >> 4, bb = row & 15;
        int y = x0[bb * 2048 + t];
        int hi = y >> 6;
        float cand = hi == 0 ? l0 : (hi == 1 ? l1 : (hi == 2 ? l2 : l3));
        float ly = __shfl(cand, y & 63, 64);
        if (lane == 0) out[row] = (lse - ly) * 1.4426950408889634f;
    }
}

extern "C" void kernel_launch(void* const* d_in, const int* in_sizes, int n_in,
                              void* d_out, int out_size, void* d_ws, size_t ws_size,
                              hipStream_t stream) {
    const int*   x0    = (const int*)d_in[0];
    const float* emb   = (const float*)d_in[1];
    const float* Wencw = (const float*)d_in[2];
    const float* Wencb = (const float*)d_in[3];
    const float* Wdecw = (const float*)d_in[4];
    const float* Wdecb = (const float*)d_in[5];
    const float* bencw = (const float*)d_in[6];
    const float* bencb = (const float*)d_in[7];
    const float* bdecw = (const float*)d_in[8];
    const float* bdecb = (const float*)d_in[9];
    const float* decw  = (const float*)d_in[10];
    const float* decb  = (const float*)d_in[11];
    float* out = (float*)d_out;

    char* ws = (char*)d_ws;
    us_t*   WdG   = (us_t*)(ws);                 //       0 .. 524288
    us_t*   decwY = (us_t*)(ws + 524288);        //  524288 .. 557056
    us_t*   EWmG  = (us_t*)(ws + 557056);        //  557056 .. 573440 (16 KB)
    u64_t*  pxbA  = (u64_t*)(ws + 573440);       //  573440 .. 638976 (64 KB agent)
    float*  T     = (float*)(ws + 638976);       //  638976 .. 9027584 (8 MB)
    uint_t* mh32  = (uint_t*)T;                  //  alias: T dead after build_P (4 MB)
    u64_t*  pxbL  = (u64_t*)(ws + 638976 + 4194304);  // 64 KB in T's dead tail
    uint_t* claimed = (uint_t*)(ws + 638976 + 4194304 + 65536);  // 256 B
    float*  P     = (float*)(ws + 9027584);      // 9027584 .. 25804800 (16 MB)

    static const int kRecurLds = 157632;
    (void)hipFuncSetAttribute((const void*)recur,
                              hipFuncAttributeMaxDynamicSharedMemorySize,
                              kRecurLds);

    cvt_kernel<<<1120, 256, 0, stream>>>(Wdecw, decw, Wencw, bencw,
                                         WdG, decwY, EWmG);
    build_T<<<16384, 128, 0, stream>>>(emb, Wencw, bencw, T);
    build_P<<<32768, 128, 0, stream>>>(T, x0, Wencb, bencb, P);
    // zero mailboxes (tag 0 never matches t+1 >= 1) and the claim table.
    // Must be after build_P: pxbL/claimed alias T's dead tail.
    (void)hipMemsetAsync(pxbA, 0, 65536, stream);
    (void)hipMemsetAsync(pxbL, 0, 65536 + 256, stream);
    recur<<<256, 512, kRecurLds, stream>>>(bdecw, bdecb, Wdecb, WdG, EWmG,
                                           P, mh32, pxbA, pxbL, claimed);
    loss_kernel<<<1024, 256, 0, stream>>>((const us_t*)mh32, decwY, decb, x0, out);
}